// Round 1
// baseline (10768.514 us; speedup 1.0000x reference)
//
#include <hip/hip_runtime.h>
#include <hip/hip_bf16.h>

#define NBLK 64
#define NTHR 256

typedef __attribute__((ext_vector_type(8))) short short8;
typedef __attribute__((ext_vector_type(4))) float f32x4;

constexpr int B = 32, T = 512, D = 1024;
constexpr int JW = D / NBLK;  // 16 h-columns per block
static_assert(JW * NBLK == D, "partition");

__device__ __forceinline__ unsigned short f2bf(float f) {
  unsigned u = __builtin_bit_cast(unsigned, f);
  u += 0x7FFFu + ((u >> 16) & 1u);   // RNE
  return (unsigned short)(u >> 16);
}

__device__ __forceinline__ float sigm(float v) {
  return 1.0f / (1.0f + __expf(-v));
}

__device__ __forceinline__ float tanh_fast(float v) {
  v = fminf(fmaxf(v, -30.0f), 30.0f);
  float e = __expf(2.0f * v);
  return (e - 1.0f) / (e + 1.0f);
}

__global__ void __launch_bounds__(NTHR, 1) lstm_persistent(
    const float* __restrict__ x,
    const float* __restrict__ W1, const float* __restrict__ b1,
    const float* __restrict__ W2, const float* __restrict__ b2,
    const float* __restrict__ W3, const float* __restrict__ b3,
    const float* __restrict__ W4, const float* __restrict__ b4,
    const float* __restrict__ bias,
    float* __restrict__ out,          // [B,T,D] then cT [B,D] then hT [B,D]
    unsigned int* __restrict__ bar,   // monotonic barrier counter (zeroed per launch)
    unsigned short* __restrict__ sbuf) // [2][B][D] bf16 bits, double-buffered s_t
{
  __shared__ float zx[4][B][JW];      // 8 KB gate-exchange

  const int blk  = blockIdx.x;
  const int tid  = threadIdx.x;
  const int wave = tid >> 6;          // 0..3 == gate index
  const int lane = tid & 63;
  const int j0   = blk * JW;

  const int col = lane & 15;          // A-row (m) and B-col (n) within tile
  const int kg  = (lane >> 4) * 8;    // k sub-offset within a K=32 step

  // ---- one-time: load this wave's weight slice into registers as bf16 B-frags ----
  // z = s @ Wcat, Wcat col (gate g, j) over k is row j of W_{g+1}  (nn.Linear W^T)
  const float* Wsrc = (wave == 0) ? W1 : (wave == 1) ? W2 : (wave == 2) ? W3 : W4;
  const float* wrow = Wsrc + (size_t)(j0 + col) * D;
  short8 bfrag[32];
#pragma unroll
  for (int kk = 0; kk < 32; ++kk) {
    float4 fa = *(const float4*)(wrow + kk * 32 + kg);
    float4 fb = *(const float4*)(wrow + kk * 32 + kg + 4);
    short8 v;
    v[0] = (short)f2bf(fa.x); v[1] = (short)f2bf(fa.y);
    v[2] = (short)f2bf(fa.z); v[3] = (short)f2bf(fa.w);
    v[4] = (short)f2bf(fb.x); v[5] = (short)f2bf(fb.y);
    v[6] = (short)f2bf(fb.z); v[7] = (short)f2bf(fb.w);
    bfrag[kk] = v;
  }

  // ---- per-thread gate-math assignment: batch row gb, column pair (jp, jp+1) ----
  const int gb   = tid >> 3;          // 0..31
  const int jp   = (tid & 7) * 2;     // 0,2,..,14
  const int jcol = j0 + jp;           // global h column

  const float bsum0 = bias[jcol], bsum1 = bias[jcol + 1];
  const float bf0 = b1[jcol] + bsum0, bf1 = b1[jcol + 1] + bsum1;
  const float bi0 = b2[jcol] + bsum0, bi1 = b2[jcol + 1] + bsum1;
  const float bg0 = b3[jcol] + bsum0, bg1 = b3[jcol + 1] + bsum1;
  const float bo0 = b4[jcol] + bsum0, bo1 = b4[jcol + 1] + bsum1;

  // ---- init s_0 = x[:,0,:] (own slice) ----
  {
    float x0 = x[(size_t)gb * T * D + jcol];
    float x1 = x[(size_t)gb * T * D + jcol + 1];
    *(unsigned*)(sbuf + (size_t)gb * D + jcol) =
        (unsigned)f2bf(x0) | ((unsigned)f2bf(x1) << 16);
  }

  float c0 = 0.0f, c1 = 0.0f;

  // barrier after s_0 publish
  __threadfence();
  __syncthreads();
  if (tid == 0) {
    __hip_atomic_fetch_add(bar, 1u, __ATOMIC_RELEASE, __HIP_MEMORY_SCOPE_AGENT);
    while (__hip_atomic_load(bar, __ATOMIC_RELAXED, __HIP_MEMORY_SCOPE_AGENT) < (unsigned)NBLK)
      __builtin_amdgcn_s_sleep(1);
  }
  __syncthreads();
  __threadfence();

  for (int t = 0; t < T; ++t) {
    const unsigned short* s = sbuf + (size_t)(t & 1) * B * D;
    unsigned short* snext   = sbuf + (size_t)((t + 1) & 1) * B * D;

    // ---- z = s @ W slice: M=32 (2 tiles) x N=16 (this wave's gate) x K=1024 ----
    f32x4 acc0 = {0.f, 0.f, 0.f, 0.f};
    f32x4 acc1 = {0.f, 0.f, 0.f, 0.f};
    const unsigned short* a0p = s + (size_t)col * D + kg;
    const unsigned short* a1p = a0p + 16 * D;
#pragma unroll
    for (int kk = 0; kk < 32; ++kk) {
      short8 a0 = *(const short8*)(a0p + kk * 32);
      short8 a1 = *(const short8*)(a1p + kk * 32);
      acc0 = __builtin_amdgcn_mfma_f32_16x16x32_bf16(a0, bfrag[kk], acc0, 0, 0, 0);
      acc1 = __builtin_amdgcn_mfma_f32_16x16x32_bf16(a1, bfrag[kk], acc1, 0, 0, 0);
    }

    // ---- exchange z across waves (C/D layout: col=lane&15, row=(lane>>4)*4+r) ----
    {
      const int zr = (lane >> 4) * 4;
#pragma unroll
      for (int r = 0; r < 4; ++r) {
        zx[wave][zr + r][col]      = acc0[r];
        zx[wave][zr + r + 16][col] = acc1[r];
      }
    }
    __syncthreads();

    // ---- gate math for (gb, jp), (gb, jp+1) ----
    float2 zf = *(const float2*)&zx[0][gb][jp];
    float2 zi = *(const float2*)&zx[1][gb][jp];
    float2 zg = *(const float2*)&zx[2][gb][jp];
    float2 zo = *(const float2*)&zx[3][gb][jp];

    float f0 = sigm(zf.x + bf0), f1 = sigm(zf.y + bf1);
    float i0 = sigm(zi.x + bi0) * tanh_fast(zg.x + bg0);
    float i1 = sigm(zi.y + bi1) * tanh_fast(zg.y + bg1);
    c0 = c0 * f0 + i0;
    c1 = c1 * f1 + i1;
    float h0 = sigm(zo.x + bo0) * tanh_fast(c0);
    float h1 = sigm(zo.y + bo1) * tanh_fast(c1);

    *(float2*)(out + (size_t)gb * T * D + (size_t)t * D + jcol) = make_float2(h0, h1);

    if (t + 1 < T) {
      const float* xn = x + (size_t)gb * T * D + (size_t)(t + 1) * D + jcol;
      float s0v = h0 + xn[0];
      float s1v = h1 + xn[1];
      *(unsigned*)(snext + (size_t)gb * D + jcol) =
          (unsigned)f2bf(s0v) | ((unsigned)f2bf(s1v) << 16);

      // device-wide barrier: step t fully published
      __threadfence();
      __syncthreads();
      if (tid == 0) {
        __hip_atomic_fetch_add(bar, 1u, __ATOMIC_RELEASE, __HIP_MEMORY_SCOPE_AGENT);
        const unsigned tgt = (unsigned)NBLK * (unsigned)(t + 2);
        while (__hip_atomic_load(bar, __ATOMIC_RELAXED, __HIP_MEMORY_SCOPE_AGENT) < tgt)
          __builtin_amdgcn_s_sleep(1);
      }
      __syncthreads();
      __threadfence();
    } else {
      float* cT = out + (size_t)B * T * D;
      float* hT = cT + (size_t)B * D;
      *(float2*)(cT + (size_t)gb * D + jcol) = make_float2(c0, c1);
      *(float2*)(hT + (size_t)gb * D + jcol) = make_float2(h0, h1);
    }
  }
}

extern "C" void kernel_launch(void* const* d_in, const int* in_sizes, int n_in,
                              void* d_out, int out_size, void* d_ws, size_t ws_size,
                              hipStream_t stream) {
  const float* x    = (const float*)d_in[0];
  const float* W1   = (const float*)d_in[1];
  const float* b1   = (const float*)d_in[2];
  const float* W2   = (const float*)d_in[3];
  const float* b2   = (const float*)d_in[4];
  const float* W3   = (const float*)d_in[5];
  const float* b3   = (const float*)d_in[6];
  const float* W4   = (const float*)d_in[7];
  const float* b4   = (const float*)d_in[8];
  const float* bias = (const float*)d_in[9];

  unsigned int* bar    = (unsigned int*)d_ws;
  unsigned short* sbuf = (unsigned short*)((char*)d_ws + 256);  // 2*B*D bf16 = 128 KB

  hipMemsetAsync(d_ws, 0, 256, stream);  // reset barrier counter every call
  hipLaunchKernelGGL(lstm_persistent, dim3(NBLK), dim3(NTHR), 0, stream,
                     x, W1, b1, W2, b2, W3, b3, W4, b4, bias,
                     (float*)d_out, bar, sbuf);
}

// Round 2
// 3024.314 us; speedup vs baseline: 3.5606x; 3.5606x over previous
//
#include <hip/hip_runtime.h>
#include <hip/hip_bf16.h>

#define NBLK 64
#define NTHR 256

typedef __attribute__((ext_vector_type(8))) short short8;
typedef __attribute__((ext_vector_type(4))) float f32x4;

constexpr int B = 32, T = 512, D = 1024;
constexpr int JW = D / NBLK;           // 16 h-columns per block
constexpr int KW = D / 4;              // 256 K-elements per wave (K-split)
static_assert(JW * NBLK == D, "partition");

__device__ __forceinline__ unsigned short f2bf(float f) {
  unsigned u = __builtin_bit_cast(unsigned, f);
  u += 0x7FFFu + ((u >> 16) & 1u);     // RNE
  return (unsigned short)(u >> 16);
}

__device__ __forceinline__ float sigm(float v) {
  return 1.0f / (1.0f + __expf(-v));
}

__device__ __forceinline__ float tanh_fast(float v) {
  v = fminf(fmaxf(v, -30.0f), 30.0f);
  float e = __expf(2.0f * v);
  return (e - 1.0f) / (e + 1.0f);
}

// agent-scope (LLC-coherent, L2-bypass) helpers — no cache fences needed
__device__ __forceinline__ void st_u32_llc(unsigned* p, unsigned v) {
  __hip_atomic_store(p, v, __ATOMIC_RELAXED, __HIP_MEMORY_SCOPE_AGENT);
}
__device__ __forceinline__ unsigned ld_u32_llc(const unsigned* p) {
  return __hip_atomic_load(p, __ATOMIC_RELAXED, __HIP_MEMORY_SCOPE_AGENT);
}
__device__ __forceinline__ unsigned long long ld_u64_llc(const void* p) {
  return __hip_atomic_load((const unsigned long long*)p, __ATOMIC_RELAXED,
                           __HIP_MEMORY_SCOPE_AGENT);
}

struct ull2s { unsigned long long lo, hi; };

__global__ void __launch_bounds__(NTHR, 1) lstm_persistent(
    const float* __restrict__ x,
    const float* __restrict__ W1, const float* __restrict__ b1,
    const float* __restrict__ W2, const float* __restrict__ b2,
    const float* __restrict__ W3, const float* __restrict__ b3,
    const float* __restrict__ W4, const float* __restrict__ b4,
    const float* __restrict__ bias,
    float* __restrict__ out,            // [B,T,D] ++ cT [B,D] ++ hT [B,D]
    unsigned* __restrict__ flags,       // [NBLK] step counters, 128B-strided
    unsigned short* __restrict__ sbuf)  // [2][B][D] bf16 bits, double-buffered
{
  __shared__ float zx[4][B][66];        // padded: stride 66 floats breaks bank aliasing

  const int blk  = blockIdx.x;
  const int tid  = threadIdx.x;
  const int wave = tid >> 6;
  const int lane = tid & 63;
  const int j0   = blk * JW;

  const int col   = lane & 15;          // m-row / n-col within 16x16 tile
  const int kg    = (lane >> 4) * 8;    // k sub-offset within a K=32 step
  const int kbase = wave * KW;          // this wave's K slice

  // ---- one-time: weights for ALL 4 gates over this wave's K slice ----
  // z col (gate g, j): k-major row j of W_{g+1}  (nn.Linear s @ W^T)
  const float* Wg[4] = {W1, W2, W3, W4};
  short8 bfrag[4][8];
#pragma unroll
  for (int g = 0; g < 4; ++g) {
    const float* wrow = Wg[g] + (size_t)(j0 + col) * D + kbase;
#pragma unroll
    for (int kk = 0; kk < 8; ++kk) {
      float4 fa = *(const float4*)(wrow + kk * 32 + kg);
      float4 fb = *(const float4*)(wrow + kk * 32 + kg + 4);
      short8 v;
      v[0] = (short)f2bf(fa.x); v[1] = (short)f2bf(fa.y);
      v[2] = (short)f2bf(fa.z); v[3] = (short)f2bf(fa.w);
      v[4] = (short)f2bf(fb.x); v[5] = (short)f2bf(fb.y);
      v[6] = (short)f2bf(fb.z); v[7] = (short)f2bf(fb.w);
      bfrag[g][kk] = v;
    }
  }

  // ---- gate-math thread mapping: batch row gb, h-columns (jp, jp+1) ----
  const int gb   = tid >> 3;            // 0..31
  const int jp   = (tid & 7) * 2;       // 0,2,..,14
  const int jcol = j0 + jp;

  const float bsum0 = bias[jcol], bsum1 = bias[jcol + 1];
  const float bf0 = b1[jcol] + bsum0, bf1 = b1[jcol + 1] + bsum1;
  const float bi0 = b2[jcol] + bsum0, bi1 = b2[jcol + 1] + bsum1;
  const float bg0 = b3[jcol] + bsum0, bg1 = b3[jcol + 1] + bsum1;
  const float bo0 = b4[jcol] + bsum0, bo1 = b4[jcol + 1] + bsum1;

  // ---- publish s_0 = x[:,0,:] slice via LLC stores ----
  {
    float2 x0 = *(const float2*)(x + (size_t)gb * T * D + jcol);
    st_u32_llc((unsigned*)(sbuf + (size_t)gb * D + jcol),
               (unsigned)f2bf(x0.x) | ((unsigned)f2bf(x0.y) << 16));
  }
  asm volatile("s_waitcnt vmcnt(0)" ::: "memory");
  __syncthreads();
  if (tid == 0) st_u32_llc(&flags[blk * 32], 1u);

  float c0 = 0.0f, c1 = 0.0f;

  for (int t = 0; t < T; ++t) {
    const unsigned short* s = sbuf + (size_t)(t & 1) * B * D;
    unsigned short* snext   = sbuf + (size_t)((t + 1) & 1) * B * D;

    // prefetch x[t+1] slice (normal cached load, in flight during the poll)
    float xa = 0.0f, xb = 0.0f;
    if (t + 1 < T) {
      float2 xn = *(const float2*)(x + (size_t)gb * T * D + (size_t)(t + 1) * D + jcol);
      xa = xn.x; xb = xn.y;
    }

    // ---- wait only for the 16 producers of this wave's K slice ----
    {
      const unsigned tgt = (unsigned)(t + 1);
      const int prod = wave * 16 + (lane & 15);
      for (;;) {
        unsigned f = (lane < 16) ? ld_u32_llc(&flags[prod * 32]) : tgt;
        if (__all((int)(f >= tgt))) break;
        __builtin_amdgcn_s_sleep(1);
      }
    }
    __builtin_amdgcn_sched_barrier(0);

    // ---- z partial: M=32 x N=64 (4 gates x 16) x K=256 (this wave) ----
    f32x4 acc[2][4];
#pragma unroll
    for (int mt = 0; mt < 2; ++mt)
#pragma unroll
      for (int g = 0; g < 4; ++g) acc[mt][g] = (f32x4){0.f, 0.f, 0.f, 0.f};

    const unsigned short* a0p = s + (size_t)col * D + kbase + kg;
    const unsigned short* a1p = a0p + 16 * D;
#pragma unroll
    for (int kk = 0; kk < 8; ++kk) {
      ull2s u0, u1;
      u0.lo = ld_u64_llc(a0p + kk * 32);
      u0.hi = ld_u64_llc(a0p + kk * 32 + 4);
      u1.lo = ld_u64_llc(a1p + kk * 32);
      u1.hi = ld_u64_llc(a1p + kk * 32 + 4);
      short8 a0 = __builtin_bit_cast(short8, u0);
      short8 a1 = __builtin_bit_cast(short8, u1);
#pragma unroll
      for (int g = 0; g < 4; ++g) {
        acc[0][g] = __builtin_amdgcn_mfma_f32_16x16x32_bf16(a0, bfrag[g][kk], acc[0][g], 0, 0, 0);
        acc[1][g] = __builtin_amdgcn_mfma_f32_16x16x32_bf16(a1, bfrag[g][kk], acc[1][g], 0, 0, 0);
      }
    }

    // ---- exchange partials (C/D layout: n=lane&15, m=(lane>>4)*4+r) ----
    {
      const int zr = (lane >> 4) * 4;
#pragma unroll
      for (int g = 0; g < 4; ++g)
#pragma unroll
        for (int r = 0; r < 4; ++r) {
          zx[wave][zr + r][g * 16 + col]      = acc[0][g][r];
          zx[wave][zr + r + 16][g * 16 + col] = acc[1][g][r];
        }
    }
    __syncthreads();

    // ---- reduce 4 K-partials + gate math for (gb, jp/jp+1) ----
    float zf0, zf1, zi0, zi1, zg0, zg1, zo0, zo1;
    {
      float2 f_ = *(const float2*)&zx[0][gb][jp];
      float2 i_ = *(const float2*)&zx[0][gb][16 + jp];
      float2 g_ = *(const float2*)&zx[0][gb][32 + jp];
      float2 o_ = *(const float2*)&zx[0][gb][48 + jp];
      zf0 = f_.x; zf1 = f_.y; zi0 = i_.x; zi1 = i_.y;
      zg0 = g_.x; zg1 = g_.y; zo0 = o_.x; zo1 = o_.y;
#pragma unroll
      for (int w = 1; w < 4; ++w) {
        f_ = *(const float2*)&zx[w][gb][jp];
        i_ = *(const float2*)&zx[w][gb][16 + jp];
        g_ = *(const float2*)&zx[w][gb][32 + jp];
        o_ = *(const float2*)&zx[w][gb][48 + jp];
        zf0 += f_.x; zf1 += f_.y; zi0 += i_.x; zi1 += i_.y;
        zg0 += g_.x; zg1 += g_.y; zo0 += o_.x; zo1 += o_.y;
      }
    }
    __syncthreads();   // zx reusable next step

    float f0 = sigm(zf0 + bf0), f1 = sigm(zf1 + bf1);
    float i0 = sigm(zi0 + bi0) * tanh_fast(zg0 + bg0);
    float i1 = sigm(zi1 + bi1) * tanh_fast(zg1 + bg1);
    c0 = c0 * f0 + i0;
    c1 = c1 * f1 + i1;
    float h0 = sigm(zo0 + bo0) * tanh_fast(c0);
    float h1 = sigm(zo1 + bo1) * tanh_fast(c1);

    if (t + 1 < T) {
      // publish s_{t+1} slice to LLC, drain, then raise our flag
      st_u32_llc((unsigned*)(snext + (size_t)gb * D + jcol),
                 (unsigned)f2bf(h0 + xa) | ((unsigned)f2bf(h1 + xb) << 16));
      asm volatile("s_waitcnt vmcnt(0)" ::: "memory");
      __syncthreads();
      if (tid == 0) st_u32_llc(&flags[blk * 32], (unsigned)(t + 2));
      // out store off the critical path (normal cached, visible at kernel end)
      *(float2*)(out + (size_t)gb * T * D + (size_t)t * D + jcol) = make_float2(h0, h1);
    } else {
      *(float2*)(out + (size_t)gb * T * D + (size_t)t * D + jcol) = make_float2(h0, h1);
      float* cT = out + (size_t)B * T * D;
      float* hT = cT + (size_t)B * D;
      *(float2*)(cT + (size_t)gb * D + jcol) = make_float2(c0, c1);
      *(float2*)(hT + (size_t)gb * D + jcol) = make_float2(h0, h1);
    }
  }
}

extern "C" void kernel_launch(void* const* d_in, const int* in_sizes, int n_in,
                              void* d_out, int out_size, void* d_ws, size_t ws_size,
                              hipStream_t stream) {
  const float* x    = (const float*)d_in[0];
  const float* W1   = (const float*)d_in[1];
  const float* b1   = (const float*)d_in[2];
  const float* W2   = (const float*)d_in[3];
  const float* b2   = (const float*)d_in[4];
  const float* W3   = (const float*)d_in[5];
  const float* b3   = (const float*)d_in[6];
  const float* W4   = (const float*)d_in[7];
  const float* b4   = (const float*)d_in[8];
  const float* bias = (const float*)d_in[9];

  unsigned* flags      = (unsigned*)d_ws;                          // 64 * 128B = 8 KB
  unsigned short* sbuf = (unsigned short*)((char*)d_ws + 8192);    // 2*B*D bf16 = 128 KB

  hipMemsetAsync(d_ws, 0, 8192, stream);  // reset flags every call (graph-replay safe)
  hipLaunchKernelGGL(lstm_persistent, dim3(NBLK), dim3(NTHR), 0, stream,
                     x, W1, b1, W2, b2, W3, b3, W4, b4, bias,
                     (float*)d_out, flags, sbuf);
}